// Round 2
// 3125.780 us; speedup vs baseline: 1.0264x; 1.0264x over previous
//
#include <hip/hip_runtime.h>
#include <math.h>

#define B_TOT 32768
#define DM    256
#define DS    16
#define DI    256
#define DTR   16
#define FF    512
#define ROWS  32
#define STA   260   // region-A row stride in floats (mult of 4; 260%32=4 avoids bank pile-up)

__device__ __forceinline__ float sigmoidf_(float x) { return 1.0f / (1.0f + __expf(-x)); }

extern "C" __global__ void __launch_bounds__(256, 4)
mamba_fused(const float* __restrict__ x0,
            const float* __restrict__ flow,
            const float* __restrict__ hin,
            const float* __restrict__ W_in,
            const float* __restrict__ W_x,
            const float* __restrict__ W_dt,
            const float* __restrict__ b_dt,
            const float* __restrict__ A_log,
            const float* __restrict__ Dp,
            const float* __restrict__ W1,
            const float* __restrict__ b1,
            const float* __restrict__ W2,
            const float* __restrict__ b2,
            const float* __restrict__ gamma,
            const float* __restrict__ beta,
            const float* __restrict__ W_bb,
            const float* __restrict__ b_bb,
            float* __restrict__ out,     // (B,4)
            float* __restrict__ h_new)   // (B,256,16)
{
    // LDS total: 33280 + 6144 + 512 + 256 = 40192 B  -> 4 blocks/CU
    __shared__ __align__(16) float sA[ROWS * STA];   // pos -> y -> s   (33280 B)
    __shared__ __align__(16) float sU[ROWS * 48];    // x_dbl, then ff1 chunk 32x32 (6144 B)
    __shared__ float sX0[ROWS * 4];                  // 512 B
    __shared__ float sMu[ROWS], sRstd[ROWS];         // 256 B

    const int t = threadIdx.x;
    const size_t g0 = (size_t)blockIdx.x * ROWS;

    // ---- 1. x0 tile ----
    if (t < ROWS * 4) sX0[t] = x0[g0 * 4 + t];
    __syncthreads();

    // ---- 2. sine embedding: pos[r][t] ----
    {
        const int c = t & 63, axis = t >> 6;
        // 2*pi / dim_t[c], dim_t[c] = 10000^((c>>1)/32)
        const float f = 6.28318530717958647692f * __expf(-(float)(c >> 1) * 0.2878231366242557f);
        #pragma unroll
        for (int r = 0; r < ROWS; ++r) {
            float p = sX0[r * 4 + axis] * f;
            sA[r * STA + t] = (c & 1) ? __cosf(p) : __sinf(p);
        }
    }

    // ---- 3. x_dbl = flow @ W_x.T  -> sU[r*48 + j] ----
    for (int idx = t; idx < ROWS * 48; idx += 256) {
        const int r = idx / 48, j = idx - r * 48;
        const float4* fv = (const float4*)(flow + (g0 + r) * DM);
        const float4* wv = (const float4*)(W_x + (size_t)j * DM);
        float acc = 0.f;
        #pragma unroll 8
        for (int k = 0; k < DM / 4; ++k) {
            float4 a = fv[k], b = wv[k];
            acc += a.x * b.x + a.y * b.y + a.z * b.z + a.w * b.w;
        }
        sU[idx] = acc;
    }
    __syncthreads();

    // ---- 4. GEMM1: pm = pos @ W_in.T ; ug[r] = {silu(pm[:,:256]), silu(pm[:,256:])} ----
    float2 ug[ROWS];   // .x = u = silu(pm_lo), .y = gsil = silu(pm_hi)
    {
        float acc0[ROWS], acc1[ROWS];
        #pragma unroll
        for (int r = 0; r < ROWS; ++r) { acc0[r] = 0.f; acc1[r] = 0.f; }
        const float4* w0v = (const float4*)(W_in + (size_t)t * DM);
        const float4* w1v = (const float4*)(W_in + (size_t)(t + DI) * DM);
        #pragma unroll 2
        for (int kc = 0; kc < DM / 4; ++kc) {
            float4 w0 = w0v[kc], w1 = w1v[kc];
            #pragma unroll
            for (int r = 0; r < ROWS; ++r) {
                float4 p = *(const float4*)&sA[r * STA + kc * 4];
                acc0[r] += p.x * w0.x + p.y * w0.y + p.z * w0.z + p.w * w0.w;
                acc1[r] += p.x * w1.x + p.y * w1.y + p.z * w1.z + p.w * w1.w;
            }
        }
        #pragma unroll
        for (int r = 0; r < ROWS; ++r) {
            float a = acc0[r], g = acc1[r];
            ug[r].x = a * sigmoidf_(a);
            ug[r].y = g * sigmoidf_(g);
        }
    }

    // ---- per-channel params ----
    float Wdt_row[DTR], Arow[DS];
    #pragma unroll
    for (int k = 0; k < DTR; ++k) Wdt_row[k] = W_dt[t * DTR + k];
    #pragma unroll
    for (int n = 0; n < DS; ++n) Arow[n] = -__expf(A_log[t * DS + n]);
    const float bdt = b_dt[t];
    const float Dt = Dp[t];

    __syncthreads();   // pos reads done; sA region will take y

    // ---- 5. SSM (single step) + write y*silu(gate) directly into sA ----
    #pragma unroll
    for (int r = 0; r < ROWS; ++r) {
        const size_t hbase = ((g0 + r) * DI + t) * DS;
        const float4* hv = (const float4*)(hin + hbase);
        float hi[16];
        *(float4*)&hi[0]  = hv[0];          // issue HBM loads first
        *(float4*)&hi[4]  = hv[1];
        *(float4*)&hi[8]  = hv[2];
        *(float4*)&hi[12] = hv[3];
        const float* xd = &sU[r * 48];
        float d = bdt;
        #pragma unroll
        for (int k = 0; k < DTR; ++k) d += xd[k] * Wdt_row[k];
        d = (d > 20.f) ? d : __logf(1.f + __expf(d));   // softplus (hides load latency)
        const float uvv = ug[r].x;
        const float du = d * uvv;
        float ysum = 0.f;
        #pragma unroll
        for (int n = 0; n < DS; ++n) {
            float dA = __expf(d * Arow[n]);
            float v = dA * hi[n] + du * xd[16 + n];
            hi[n] = v;                       // in-place: h_new value
            ysum += v * xd[32 + n];
        }
        float4* ho = (float4*)(h_new + hbase);
        ho[0] = *(const float4*)&hi[0];
        ho[1] = *(const float4*)&hi[4];
        ho[2] = *(const float4*)&hi[8];
        ho[3] = *(const float4*)&hi[12];
        sA[r * STA + t] = (ysum + uvv * Dt) * ug[r].y;
    }
    __syncthreads();

    // ---- 7. FFN: src2 = relu(y@W1.T + b1) @ W2.T  (chunks of 32 FF cols, 4 KB stage) ----
    float acc2[ROWS];
    #pragma unroll
    for (int r = 0; r < ROWS; ++r) acc2[r] = 0.f;
    const int rr = t >> 3;            // row 0..31
    const int j4 = (t & 7) * 4;       // 4 FF cols per thread
    for (int jc = 0; jc < FF; jc += 32) {
        float fa[4];
        #pragma unroll
        for (int q = 0; q < 4; ++q) fa[q] = b1[jc + j4 + q];
        #pragma unroll 2
        for (int kc = 0; kc < DM / 4; ++kc) {
            float4 yv4 = *(const float4*)&sA[rr * STA + kc * 4];
            #pragma unroll
            for (int q = 0; q < 4; ++q) {
                float4 w = *(const float4*)&W1[(size_t)(jc + j4 + q) * DM + kc * 4];
                fa[q] += yv4.x * w.x + yv4.y * w.y + yv4.z * w.z + yv4.w * w.w;
            }
        }
        float4 f4;
        f4.x = fmaxf(fa[0], 0.f); f4.y = fmaxf(fa[1], 0.f);
        f4.z = fmaxf(fa[2], 0.f); f4.w = fmaxf(fa[3], 0.f);
        *(float4*)&sU[rr * 32 + j4] = f4;
        __syncthreads();
        const float4* w2v = (const float4*)(W2 + (size_t)t * FF + jc);
        #pragma unroll
        for (int jj = 0; jj < 8; ++jj) {
            float4 w = w2v[jj];
            #pragma unroll
            for (int r = 0; r < ROWS; ++r) {
                float4 fv4 = *(const float4*)&sU[r * 32 + jj * 4];
                acc2[r] += fv4.x * w.x + fv4.y * w.y + fv4.z * w.z + fv4.w * w.w;
            }
        }
        __syncthreads();
    }

    // ---- 8. s = y + src2 + b2 (thread t owns column t exclusively: no barrier needed) ----
    {
        const float b2t = b2[t];
        #pragma unroll
        for (int r = 0; r < ROWS; ++r) sA[r * STA + t] += acc2[r] + b2t;
    }
    __syncthreads();

    // ---- 9. layernorm stats (shfl width-8, no LDS scratch) ----
    {
        const int r = t >> 3, q = t & 7;
        float s1 = 0.f, s2s = 0.f;
        #pragma unroll
        for (int k4 = 0; k4 < 8; ++k4) {
            float4 v = *(const float4*)&sA[r * STA + q * 32 + k4 * 4];
            s1  += v.x + v.y + v.z + v.w;
            s2s += v.x * v.x + v.y * v.y + v.z * v.z + v.w * v.w;
        }
        s1 += __shfl_xor(s1, 1);  s2s += __shfl_xor(s2s, 1);
        s1 += __shfl_xor(s1, 2);  s2s += __shfl_xor(s2s, 2);
        s1 += __shfl_xor(s1, 4);  s2s += __shfl_xor(s2s, 4);
        if (q == 0) {
            const float mu  = s1 * (1.f / DM);
            const float var = s2s * (1.f / DM) - mu * mu;
            sMu[r]   = mu;
            sRstd[r] = rsqrtf(var + 1e-5f);
        }
    }
    __syncthreads();

    // ---- 10. out = sigmoid(LN(s) @ W_bb.T + b_bb)  — all 256 threads, 2 per output ----
    {
        const int r = t >> 3, c = (t >> 1) & 3, hf = t & 1;
        const float mu = sMu[r], rstd = sRstd[r];
        float acc = 0.f;
        const int i0 = hf * 128;
        #pragma unroll 8
        for (int i4 = 0; i4 < 32; ++i4) {
            const int i = i0 + i4 * 4;
            float4 sv = *(const float4*)&sA[r * STA + i];
            float4 gm = *(const float4*)&gamma[i];
            float4 bt = *(const float4*)&beta[i];
            float4 wb = *(const float4*)&W_bb[c * DM + i];
            acc += ((sv.x - mu) * rstd * gm.x + bt.x) * wb.x
                 + ((sv.y - mu) * rstd * gm.y + bt.y) * wb.y
                 + ((sv.z - mu) * rstd * gm.z + bt.z) * wb.z
                 + ((sv.w - mu) * rstd * gm.w + bt.w) * wb.w;
        }
        acc += __shfl_xor(acc, 1);
        if (hf == 0) out[(g0 + r) * 4 + c] = sigmoidf_(acc + b_bb[c]);
    }
}

extern "C" void kernel_launch(void* const* d_in, const int* in_sizes, int n_in,
                              void* d_out, int out_size, void* d_ws, size_t ws_size,
                              hipStream_t stream) {
    const float* x0    = (const float*)d_in[0];
    const float* flow  = (const float*)d_in[1];
    const float* hin   = (const float*)d_in[2];
    const float* W_in  = (const float*)d_in[3];
    const float* W_x   = (const float*)d_in[4];
    const float* W_dt  = (const float*)d_in[5];
    const float* b_dt  = (const float*)d_in[6];
    const float* A_log = (const float*)d_in[7];
    const float* Dp    = (const float*)d_in[8];
    const float* W1    = (const float*)d_in[9];
    const float* b1    = (const float*)d_in[10];
    const float* W2    = (const float*)d_in[11];
    const float* b2    = (const float*)d_in[12];
    const float* gamma = (const float*)d_in[13];
    const float* beta  = (const float*)d_in[14];
    const float* W_bb  = (const float*)d_in[15];
    const float* b_bb  = (const float*)d_in[16];

    float* out   = (float*)d_out;
    float* h_new = out + (size_t)B_TOT * 4;

    dim3 grid(B_TOT / ROWS), block(256);
    hipLaunchKernelGGL(mamba_fused, grid, block, 0, stream,
                       x0, flow, hin, W_in, W_x, W_dt, b_dt, A_log, Dp,
                       W1, b1, W2, b2, gamma, beta, W_bb, b_bb, out, h_new);
}